// Round 1
// baseline (1607.322 us; speedup 1.0000x reference)
//
#include <hip/hip_runtime.h>
#include <math.h>

// ---------------------------------------------------------------------------
// temporalGNN: 3x GCN encoder (shared weights) -> mean pool -> LSTM(T=3) ->
// attention -> MLP head.  All fp32.
// ---------------------------------------------------------------------------

#define HD 64           // hidden dim
#define TT 3            // timesteps / channels

__device__ __forceinline__ float sigmoidf_(float x) { return 1.f / (1.f + expf(-x)); }

// ---- degree: deg[dst] += 1 ------------------------------------------------
__global__ void deg_kernel(const int* __restrict__ dst, float* __restrict__ deg, int E) {
    int e = blockIdx.x * blockDim.x + threadIdx.x;
    if (e < E) atomicAdd(&deg[dst[e]], 1.0f);
}

// ---- dinv = rsqrt(deg + 2) (in place) -------------------------------------
__global__ void dinv_kernel(float* __restrict__ deg, int N) {
    int n = blockIdx.x * blockDim.x + threadIdx.x;
    if (n < N) deg[n] = rsqrtf(deg[n] + 2.0f);
}

// ---- cnt[batch[n]] += 1 ---------------------------------------------------
__global__ void cnt_kernel(const int* __restrict__ batch, float* __restrict__ cnt, int N) {
    int n = blockIdx.x * blockDim.x + threadIdx.x;
    if (n < N) atomicAdd(&cnt[batch[n]], 1.0f);
}

// ---- GEMM: C[N,64] = A[N,64(lda)] @ W[64,64] (+bias) ----------------------
// one block = 64 rows x 64 cols, 256 threads, LDS-staged A tile + W.
__global__ __launch_bounds__(256) void gemm64_kernel(
    const float* __restrict__ A, int lda, const float* __restrict__ W,
    const float* __restrict__ bias, float* __restrict__ C, int nrows) {
    __shared__ float As[64][68];
    __shared__ float Ws[64][68];
    const int t = threadIdx.x;
    const int r0 = blockIdx.x * 64;

    #pragma unroll
    for (int i = 0; i < 4; ++i) {                 // load W (64x64) as float4
        int idx = t + i * 256;                    // 0..1023
        int k = idx >> 4, c4 = idx & 15;
        float4 w = *(const float4*)(W + k * 64 + c4 * 4);
        *(float4*)(&Ws[k][c4 * 4]) = w;
    }
    #pragma unroll
    for (int i = 0; i < 4; ++i) {                 // load A tile (64x64)
        int idx = t + i * 256;
        int row = idx >> 4, c4 = idx & 15;
        int gr = r0 + row;
        float4 a = make_float4(0.f, 0.f, 0.f, 0.f);
        if (gr < nrows) a = *(const float4*)(A + (long)gr * lda + c4 * 4);
        *(float4*)(&As[row][c4 * 4]) = a;
    }
    __syncthreads();

    const int row = t >> 2;
    const int c0 = (t & 3) * 16;
    float acc[16];
    #pragma unroll
    for (int j = 0; j < 16; ++j) acc[j] = 0.f;
    #pragma unroll 8
    for (int k = 0; k < 64; ++k) {
        float a = As[row][k];
        #pragma unroll
        for (int j = 0; j < 16; ++j) acc[j] = fmaf(a, Ws[k][c0 + j], acc[j]);
    }
    int gr = r0 + row;
    if (gr < nrows) {
        float* Cp = C + (long)gr * 64 + c0;
        #pragma unroll
        for (int j = 0; j < 16; ++j) Cp[j] = acc[j] + (bias ? bias[c0 + j] : 0.f);
    }
}

// ---- edge scatter: agg[dst] += dinv[src]*dinv[dst] * xw[src] --------------
// one wave (64 lanes) per edge; lane = feature index.
__global__ void scatter_kernel(const int* __restrict__ src, const int* __restrict__ dst,
                               const float* __restrict__ dinv, const float* __restrict__ xw,
                               float* __restrict__ agg, int E) {
    long tid = (long)blockIdx.x * blockDim.x + threadIdx.x;
    int e = (int)(tid >> 6);
    int j = (int)(tid & 63);
    if (e >= E) return;
    int s = src[e], d = dst[e];
    float norm = dinv[s] * dinv[d];
    atomicAdd(&agg[(long)d * 64 + j], norm * xw[(long)s * 64 + j]);
}

// ---- combine: out = maybe_relu(agg + 2*dinv^2*xw + b) + prev --------------
template <bool RELU>
__global__ void combine_kernel(const float* __restrict__ agg, const float* __restrict__ xw,
                               const float* __restrict__ bias, const float* __restrict__ dinv,
                               const float* __restrict__ prev, float* __restrict__ outp, int N) {
    long tid = (long)blockIdx.x * blockDim.x + threadIdx.x;
    if (tid >= (long)N * 64) return;
    int n = (int)(tid >> 6);
    int j = (int)(tid & 63);
    float di = dinv[n];
    float val = agg[tid] + 2.f * di * di * xw[tid] + bias[j];
    if (RELU) val = fmaxf(val, 0.f);
    outp[tid] = val + prev[tid];
}

// ---- pool: seq[batch[n], chan, :] += out2[n, :] ---------------------------
__global__ void pool_kernel(const float* __restrict__ out2, const int* __restrict__ batch,
                            float* __restrict__ seq, int chan, int N) {
    long tid = (long)blockIdx.x * blockDim.x + threadIdx.x;
    int n = (int)(tid >> 6);
    int j = (int)(tid & 63);
    if (n >= N) return;
    int b = batch[n];
    atomicAdd(&seq[((long)b * TT + chan) * 64 + j], out2[(long)n * 64 + j]);
}

// ---- head: mean, LSTM(3), attention, MLP; one block per batch element ------
__global__ __launch_bounds__(256) void head_kernel(
    const float* __restrict__ seq, const float* __restrict__ cnt,
    const float* __restrict__ h0, const float* __restrict__ c0,
    const float* __restrict__ Wih, const float* __restrict__ Whh,
    const float* __restrict__ bih, const float* __restrict__ bhh,
    const float* __restrict__ w0W, const float* __restrict__ w0b,
    const float* __restrict__ attnW, const float* __restrict__ attnb,
    const float* __restrict__ l1W, const float* __restrict__ l1b,
    const float* __restrict__ l2W, const float* __restrict__ l2b,
    const float* __restrict__ cov, float* __restrict__ out_attn,
    float* __restrict__ out_cls) {
    const int b = blockIdx.x;
    const int t = threadIdx.x;

    __shared__ float x[TT][64];
    __shared__ float h[64], c[64];
    __shared__ float gates[256];
    __shared__ float rnn[TT][64];
    __shared__ float r[TT][64];
    __shared__ float logit[TT];
    __shared__ float a[TT];
    __shared__ float pooled[64];
    __shared__ float l1o[16];

    float inv = 1.0f / fmaxf(cnt[b], 1.0f);
    if (t < TT * 64) x[t / 64][t % 64] = seq[(long)b * TT * 64 + t] * inv;
    if (t < 64) { h[t] = h0[(long)b * 64 + t]; c[t] = c0[(long)b * 64 + t]; }
    __syncthreads();

    for (int step = 0; step < TT; ++step) {
        float g = bih[t] + bhh[t];
        const float* wi = Wih + (long)t * 64;
        const float* wh = Whh + (long)t * 64;
        #pragma unroll 8
        for (int k = 0; k < 64; ++k) g += wi[k] * x[step][k] + wh[k] * h[k];
        gates[t] = g;
        __syncthreads();
        if (t < 64) {
            float ig = sigmoidf_(gates[t]);
            float fg = sigmoidf_(gates[64 + t]);
            float gg = tanhf(gates[128 + t]);
            float og = sigmoidf_(gates[192 + t]);
            float cn = fg * c[t] + ig * gg;
            c[t] = cn;
            float hn = og * tanhf(cn);
            h[t] = hn;
            rnn[step][t] = hn;
        }
        __syncthreads();
    }

    // r = tanh(rnn @ w0W^T + w0b): 192 elements
    if (t < TT * 64) {
        int tt = t / 64, j = t % 64;
        float v = w0b[j];
        const float* wr = w0W + (long)j * 64;
        #pragma unroll 8
        for (int k = 0; k < 64; ++k) v += rnn[tt][k] * wr[k];
        r[tt][j] = tanhf(v);
    }
    __syncthreads();

    if (t < TT) {
        float v = attnb[0];
        #pragma unroll 8
        for (int k = 0; k < 64; ++k) v += r[t][k] * attnW[k];
        logit[t] = v;
    }
    __syncthreads();

    if (t == 0) {
        float m = fmaxf(logit[0], fmaxf(logit[1], logit[2]));
        float e0 = expf(logit[0] - m), e1 = expf(logit[1] - m), e2 = expf(logit[2] - m);
        float s = e0 + e1 + e2;
        a[0] = e0 / s; a[1] = e1 / s; a[2] = e2 / s;
        out_attn[(long)b * TT + 0] = a[0];
        out_attn[(long)b * TT + 1] = a[1];
        out_attn[(long)b * TT + 2] = a[2];
    }
    __syncthreads();

    if (t < 64) pooled[t] = a[0] * r[0][t] + a[1] * r[1][t] + a[2] * r[2][t];
    __syncthreads();

    if (t < 8) {
        float v = l1b[t];
        const float* w = l1W + (long)t * 64;
        #pragma unroll 8
        for (int k = 0; k < 64; ++k) v += pooled[k] * w[k];
        l1o[t] = fmaxf(v, 0.f);
    } else if (t < 16) {
        l1o[t] = cov[(long)b * 8 + (t - 8)];
    }
    __syncthreads();

    if (t < 2) {
        float v = l2b[t];
        const float* w = l2W + (long)t * 16;
        #pragma unroll
        for (int k = 0; k < 16; ++k) v += l1o[k] * w[k];
        out_cls[(long)b * 2 + t] = v;
    }
}

// ---------------------------------------------------------------------------
extern "C" void kernel_launch(void* const* d_in, const int* in_sizes, int n_in,
                              void* d_out, int out_size, void* d_ws, size_t ws_size,
                              hipStream_t stream) {
    const float* x       = (const float*)d_in[0];   // [N, 192]
    const int*   eidx    = (const int*)d_in[1];     // [2, E]
    const float* cov     = (const float*)d_in[2];   // [B, 8]
    const int*   batch   = (const int*)d_in[3];     // [N]
    const float* h0      = (const float*)d_in[4];
    const float* c0      = (const float*)d_in[5];
    const float* lin_W   = (const float*)d_in[6];
    const float* lin_b   = (const float*)d_in[7];
    const float* conv1_W = (const float*)d_in[8];
    const float* conv1_b = (const float*)d_in[9];
    const float* conv2_W = (const float*)d_in[10];
    const float* conv2_b = (const float*)d_in[11];
    const float* Wih     = (const float*)d_in[12];
    const float* Whh     = (const float*)d_in[13];
    const float* bih     = (const float*)d_in[14];
    const float* bhh     = (const float*)d_in[15];
    const float* w0_W    = (const float*)d_in[16];
    const float* w0_b    = (const float*)d_in[17];
    const float* attn_W  = (const float*)d_in[18];
    const float* attn_b  = (const float*)d_in[19];
    const float* l1_W    = (const float*)d_in[20];
    const float* l1_b    = (const float*)d_in[21];
    const float* l2_W    = (const float*)d_in[22];
    const float* l2_b    = (const float*)d_in[23];

    const int N = in_sizes[3];
    const int E = in_sizes[1] / 2;
    const int B = in_sizes[2] / 8;

    const int* src = eidx;
    const int* dst = eidx + E;

    // workspace layout (floats)
    float* ws      = (float*)d_ws;
    float* dinv    = ws;                       // [N]   (deg first, then rsqrt in place)
    float* cnt     = dinv + N;                 // [B]
    float* seq     = cnt + B;                  // [B,3,64]
    float* buf0    = seq + (long)B * TT * 64;  // [N,64]
    float* buf1    = buf0 + (long)N * 64;      // [N,64]
    float* buf2    = buf1 + (long)N * 64;      // [N,64]

    float* out_attn = (float*)d_out;           // [B,3]
    float* out_cls  = out_attn + (long)B * TT; // [B,2]

    auto cdiv = [](long a, long b) { return (int)((a + b - 1) / b); };

    // degree / dinv / counts / seq init
    hipMemsetAsync(dinv, 0, (size_t)N * 4, stream);
    hipMemsetAsync(cnt, 0, (size_t)B * 4, stream);
    hipMemsetAsync(seq, 0, (size_t)B * TT * 64 * 4, stream);
    deg_kernel<<<cdiv(E, 256), 256, 0, stream>>>(dst, dinv, E);
    cnt_kernel<<<cdiv(N, 256), 256, 0, stream>>>(batch, cnt, N);
    dinv_kernel<<<cdiv(N, 256), 256, 0, stream>>>(dinv, N);

    const int gemm_grid  = cdiv(N, 64);
    const int ew_grid    = cdiv((long)E * 64, 256);
    const int nw_grid    = cdiv((long)N * 64, 256);

    for (int ch = 0; ch < TT; ++ch) {
        // out0 = x_slice @ lin_W + lin_b        -> buf0
        gemm64_kernel<<<gemm_grid, 256, 0, stream>>>(x + ch * 64, 3 * 64, lin_W, lin_b, buf0, N);
        // xw1 = out0 @ conv1_W                  -> buf1
        gemm64_kernel<<<gemm_grid, 256, 0, stream>>>(buf0, 64, conv1_W, nullptr, buf1, N);
        // agg1 = scatter                        -> buf2
        hipMemsetAsync(buf2, 0, (size_t)N * 64 * 4, stream);
        scatter_kernel<<<ew_grid, 256, 0, stream>>>(src, dst, dinv, buf1, buf2, E);
        // out1 = relu(agg1 + 2 dinv^2 xw1 + b1) + out0   -> buf2 (in place)
        combine_kernel<true><<<nw_grid, 256, 0, stream>>>(buf2, buf1, conv1_b, dinv, buf0, buf2, N);
        // xw2 = out1 @ conv2_W                  -> buf1
        gemm64_kernel<<<gemm_grid, 256, 0, stream>>>(buf2, 64, conv2_W, nullptr, buf1, N);
        // agg2 = scatter                        -> buf0
        hipMemsetAsync(buf0, 0, (size_t)N * 64 * 4, stream);
        scatter_kernel<<<ew_grid, 256, 0, stream>>>(src, dst, dinv, buf1, buf0, E);
        // out2 = (agg2 + 2 dinv^2 xw2 + b2) + out1       -> buf0 (in place)
        combine_kernel<false><<<nw_grid, 256, 0, stream>>>(buf0, buf1, conv2_b, dinv, buf2, buf0, N);
        // pool into seq[:, ch, :]
        pool_kernel<<<nw_grid, 256, 0, stream>>>(buf0, batch, seq, ch, N);
    }

    head_kernel<<<B, 256, 0, stream>>>(seq, cnt, h0, c0, Wih, Whh, bih, bhh,
                                       w0_W, w0_b, attn_W, attn_b, l1_W, l1_b,
                                       l2_W, l2_b, cov, out_attn, out_cls);
}

// Round 3
// 830.349 us; speedup vs baseline: 1.9357x; 1.9357x over previous
//
#include <hip/hip_runtime.h>
#include <math.h>

// ---------------------------------------------------------------------------
// temporalGNN: 3x GCN encoder (shared weights) -> mean pool -> LSTM(T=3) ->
// attention -> MLP head.  All fp32.
// R2: scatter -> CSR gather (no float atomics), fused combine, range pool.
// (resubmit after container failure)
// ---------------------------------------------------------------------------

#define TT 3

__device__ __forceinline__ float sigmoidf_(float x) { return 1.f / (1.f + expf(-x)); }

// ---- integer degree / batch counts ----------------------------------------
__global__ void degi_kernel(const int* __restrict__ dst, int* __restrict__ deg, int E) {
    int e = blockIdx.x * blockDim.x + threadIdx.x;
    if (e < E) atomicAdd(&deg[dst[e]], 1);
}
__global__ void cnti_kernel(const int* __restrict__ batch, int* __restrict__ cnt, int N) {
    int n = blockIdx.x * blockDim.x + threadIdx.x;
    if (n < N) atomicAdd(&cnt[batch[n]], 1);
}
__global__ void dinv_kernel(const int* __restrict__ deg, float* __restrict__ dinv, int N) {
    int n = blockIdx.x * blockDim.x + threadIdx.x;
    if (n < N) dinv[n] = rsqrtf((float)deg[n] + 2.0f);
}

// ---- exclusive scan (3-kernel: local, block-sums, add) --------------------
__global__ void scan_local(const int* __restrict__ deg, int* __restrict__ rowptr,
                           int* __restrict__ bsum, int N) {
    __shared__ int s[256];
    int i = blockIdx.x * 256 + threadIdx.x;
    int v = (i < N) ? deg[i] : 0;
    s[threadIdx.x] = v;
    __syncthreads();
    for (int off = 1; off < 256; off <<= 1) {
        int t = (threadIdx.x >= off) ? s[threadIdx.x - off] : 0;
        __syncthreads();
        s[threadIdx.x] += t;
        __syncthreads();
    }
    if (i < N) rowptr[i] = s[threadIdx.x] - v;          // exclusive
    if (threadIdx.x == 255) bsum[blockIdx.x] = s[255];
}
__global__ void scan_bsum(int* __restrict__ bsum, int nblk) {
    __shared__ int s[256];
    int v = (threadIdx.x < nblk) ? bsum[threadIdx.x] : 0;
    s[threadIdx.x] = v;
    __syncthreads();
    for (int off = 1; off < 256; off <<= 1) {
        int t = (threadIdx.x >= off) ? s[threadIdx.x - off] : 0;
        __syncthreads();
        s[threadIdx.x] += t;
        __syncthreads();
    }
    if (threadIdx.x < nblk) bsum[threadIdx.x] = s[threadIdx.x] - v;  // exclusive
}
__global__ void scan_add(int* __restrict__ rowptr, int* __restrict__ cursor,
                         const int* __restrict__ bsum, int N, int E) {
    int i = blockIdx.x * 256 + threadIdx.x;
    if (i < N) {
        int r = rowptr[i] + bsum[blockIdx.x];
        rowptr[i] = r;
        cursor[i] = r;
    }
    if (i == 0) rowptr[N] = E;
}
// single-block exclusive scan of cnt (B <= 256) -> node ranges per batch elem
__global__ void scan_brow(const int* __restrict__ cnt, int* __restrict__ brow, int B, int N) {
    __shared__ int s[256];
    int v = (threadIdx.x < B) ? cnt[threadIdx.x] : 0;
    s[threadIdx.x] = v;
    __syncthreads();
    for (int off = 1; off < 256; off <<= 1) {
        int t = (threadIdx.x >= off) ? s[threadIdx.x - off] : 0;
        __syncthreads();
        s[threadIdx.x] += t;
        __syncthreads();
    }
    if (threadIdx.x < B) brow[threadIdx.x] = s[threadIdx.x] - v;
    if (threadIdx.x == 0) brow[B] = N;
}

// ---- CSR fill: bucket edges by dst ----------------------------------------
__global__ void fill_csr(const int* __restrict__ src, const int* __restrict__ dst,
                         const float* __restrict__ dinv, int* __restrict__ cursor,
                         int* __restrict__ csrc, float* __restrict__ cw, int E) {
    int e = blockIdx.x * blockDim.x + threadIdx.x;
    if (e >= E) return;
    int s = src[e], d = dst[e];
    int p = atomicAdd(&cursor[d], 1);
    csrc[p] = s;
    cw[p] = dinv[s] * dinv[d];
}

// ---- GEMM: C[N,64] = A[N,64(lda)] @ W[64,64] (+bias) ----------------------
__global__ __launch_bounds__(256) void gemm64_kernel(
    const float* __restrict__ A, int lda, const float* __restrict__ W,
    const float* __restrict__ bias, float* __restrict__ C, int nrows) {
    __shared__ float As[64][68];
    __shared__ float Ws[64][68];
    const int t = threadIdx.x;
    const int r0 = blockIdx.x * 64;

    #pragma unroll
    for (int i = 0; i < 4; ++i) {
        int idx = t + i * 256;
        int k = idx >> 4, c4 = idx & 15;
        float4 w = *(const float4*)(W + k * 64 + c4 * 4);
        *(float4*)(&Ws[k][c4 * 4]) = w;
    }
    #pragma unroll
    for (int i = 0; i < 4; ++i) {
        int idx = t + i * 256;
        int row = idx >> 4, c4 = idx & 15;
        int gr = r0 + row;
        float4 a = make_float4(0.f, 0.f, 0.f, 0.f);
        if (gr < nrows) a = *(const float4*)(A + (long)gr * lda + c4 * 4);
        *(float4*)(&As[row][c4 * 4]) = a;
    }
    __syncthreads();

    const int row = t >> 2;
    const int c0 = (t & 3) * 16;
    float acc[16];
    #pragma unroll
    for (int j = 0; j < 16; ++j) acc[j] = 0.f;
    #pragma unroll 8
    for (int k = 0; k < 64; ++k) {
        float a = As[row][k];
        #pragma unroll
        for (int j = 0; j < 16; ++j) acc[j] = fmaf(a, Ws[k][c0 + j], acc[j]);
    }
    int gr = r0 + row;
    if (gr < nrows) {
        float* Cp = C + (long)gr * 64 + c0;
        #pragma unroll
        for (int j = 0; j < 16; ++j) Cp[j] = acc[j] + (bias ? bias[c0 + j] : 0.f);
    }
}

// ---- fused GCN step: gather + self-loop + bias (+relu) + residual ---------
// one wave per destination node; lane = feature index.
template <bool RELU>
__global__ __launch_bounds__(256) void gcn_gather(
    const int* __restrict__ rowptr, const int* __restrict__ csrc,
    const float* __restrict__ cw, const float* __restrict__ dinv,
    const float* __restrict__ xw, const float* __restrict__ bias,
    const float* __restrict__ prev, float* __restrict__ outp, int N) {
    long tid = (long)blockIdx.x * 256 + threadIdx.x;
    int n = (int)(tid >> 6);
    int j = (int)(tid & 63);
    if (n >= N) return;
    int p = rowptr[n];
    const int end = rowptr[n + 1];
    float acc = 0.f;
    for (; p + 1 < end; p += 2) {
        int s0 = csrc[p], s1 = csrc[p + 1];
        float w0 = cw[p], w1 = cw[p + 1];
        float v0 = xw[(long)s0 * 64 + j];
        float v1 = xw[(long)s1 * 64 + j];
        acc = fmaf(w0, v0, acc);
        acc = fmaf(w1, v1, acc);
    }
    if (p < end) acc = fmaf(cw[p], xw[(long)csrc[p] * 64 + j], acc);
    float di = dinv[n];
    float val = acc + 2.f * di * di * xw[tid] + bias[j];
    if (RELU) val = fmaxf(val, 0.f);
    outp[tid] = val + prev[tid];
}

// ---- range-based mean-pool numerator: seq[b,chan,:] = sum over nodes ------
__global__ __launch_bounds__(256) void pool_range(
    const float* __restrict__ out2, const int* __restrict__ brow,
    float* __restrict__ seq, int chan) {
    const int b = blockIdx.x;
    const int j = threadIdx.x & 63;
    const int w = threadIdx.x >> 6;
    __shared__ float part[4][64];
    float acc = 0.f;
    const int s = brow[b], e = brow[b + 1];
    for (int n = s + w; n < e; n += 4) acc += out2[(long)n * 64 + j];
    part[w][j] = acc;
    __syncthreads();
    if (w == 0)
        seq[((long)b * TT + chan) * 64 + j] = part[0][j] + part[1][j] + part[2][j] + part[3][j];
}

// ---- head: mean, LSTM(3), attention, MLP; one block per batch element ------
__global__ __launch_bounds__(256) void head_kernel(
    const float* __restrict__ seq, const int* __restrict__ cnt,
    const float* __restrict__ h0, const float* __restrict__ c0,
    const float* __restrict__ Wih, const float* __restrict__ Whh,
    const float* __restrict__ bih, const float* __restrict__ bhh,
    const float* __restrict__ w0W, const float* __restrict__ w0b,
    const float* __restrict__ attnW, const float* __restrict__ attnb,
    const float* __restrict__ l1W, const float* __restrict__ l1b,
    const float* __restrict__ l2W, const float* __restrict__ l2b,
    const float* __restrict__ cov, float* __restrict__ out_attn,
    float* __restrict__ out_cls) {
    const int b = blockIdx.x;
    const int t = threadIdx.x;

    __shared__ float x[TT][64];
    __shared__ float h[64], c[64];
    __shared__ float gates[256];
    __shared__ float rnn[TT][64];
    __shared__ float r[TT][64];
    __shared__ float logit[TT];
    __shared__ float a[TT];
    __shared__ float pooled[64];
    __shared__ float l1o[16];

    float inv = 1.0f / fmaxf((float)cnt[b], 1.0f);
    if (t < TT * 64) x[t / 64][t % 64] = seq[(long)b * TT * 64 + t] * inv;
    if (t < 64) { h[t] = h0[(long)b * 64 + t]; c[t] = c0[(long)b * 64 + t]; }
    __syncthreads();

    for (int step = 0; step < TT; ++step) {
        float g = bih[t] + bhh[t];
        const float* wi = Wih + (long)t * 64;
        const float* wh = Whh + (long)t * 64;
        #pragma unroll 8
        for (int k = 0; k < 64; ++k) g += wi[k] * x[step][k] + wh[k] * h[k];
        gates[t] = g;
        __syncthreads();
        if (t < 64) {
            float ig = sigmoidf_(gates[t]);
            float fg = sigmoidf_(gates[64 + t]);
            float gg = tanhf(gates[128 + t]);
            float og = sigmoidf_(gates[192 + t]);
            float cn = fg * c[t] + ig * gg;
            c[t] = cn;
            float hn = og * tanhf(cn);
            h[t] = hn;
            rnn[step][t] = hn;
        }
        __syncthreads();
    }

    if (t < TT * 64) {
        int tt = t / 64, j = t % 64;
        float v = w0b[j];
        const float* wr = w0W + (long)j * 64;
        #pragma unroll 8
        for (int k = 0; k < 64; ++k) v += rnn[tt][k] * wr[k];
        r[tt][j] = tanhf(v);
    }
    __syncthreads();

    if (t < TT) {
        float v = attnb[0];
        #pragma unroll 8
        for (int k = 0; k < 64; ++k) v += r[t][k] * attnW[k];
        logit[t] = v;
    }
    __syncthreads();

    if (t == 0) {
        float m = fmaxf(logit[0], fmaxf(logit[1], logit[2]));
        float e0 = expf(logit[0] - m), e1 = expf(logit[1] - m), e2 = expf(logit[2] - m);
        float s = e0 + e1 + e2;
        a[0] = e0 / s; a[1] = e1 / s; a[2] = e2 / s;
        out_attn[(long)b * TT + 0] = a[0];
        out_attn[(long)b * TT + 1] = a[1];
        out_attn[(long)b * TT + 2] = a[2];
    }
    __syncthreads();

    if (t < 64) pooled[t] = a[0] * r[0][t] + a[1] * r[1][t] + a[2] * r[2][t];
    __syncthreads();

    if (t < 8) {
        float v = l1b[t];
        const float* w = l1W + (long)t * 64;
        #pragma unroll 8
        for (int k = 0; k < 64; ++k) v += pooled[k] * w[k];
        l1o[t] = fmaxf(v, 0.f);
    } else if (t < 16) {
        l1o[t] = cov[(long)b * 8 + (t - 8)];
    }
    __syncthreads();

    if (t < 2) {
        float v = l2b[t];
        const float* w = l2W + (long)t * 16;
        #pragma unroll
        for (int k = 0; k < 16; ++k) v += l1o[k] * w[k];
        out_cls[(long)b * 2 + t] = v;
    }
}

// ---------------------------------------------------------------------------
extern "C" void kernel_launch(void* const* d_in, const int* in_sizes, int n_in,
                              void* d_out, int out_size, void* d_ws, size_t ws_size,
                              hipStream_t stream) {
    const float* x       = (const float*)d_in[0];
    const int*   eidx    = (const int*)d_in[1];
    const float* cov     = (const float*)d_in[2];
    const int*   batch   = (const int*)d_in[3];
    const float* h0      = (const float*)d_in[4];
    const float* c0      = (const float*)d_in[5];
    const float* lin_W   = (const float*)d_in[6];
    const float* lin_b   = (const float*)d_in[7];
    const float* conv1_W = (const float*)d_in[8];
    const float* conv1_b = (const float*)d_in[9];
    const float* conv2_W = (const float*)d_in[10];
    const float* conv2_b = (const float*)d_in[11];
    const float* Wih     = (const float*)d_in[12];
    const float* Whh     = (const float*)d_in[13];
    const float* bih     = (const float*)d_in[14];
    const float* bhh     = (const float*)d_in[15];
    const float* w0_W    = (const float*)d_in[16];
    const float* w0_b    = (const float*)d_in[17];
    const float* attn_W  = (const float*)d_in[18];
    const float* attn_b  = (const float*)d_in[19];
    const float* l1_W    = (const float*)d_in[20];
    const float* l1_b    = (const float*)d_in[21];
    const float* l2_W    = (const float*)d_in[22];
    const float* l2_b    = (const float*)d_in[23];

    const int N = in_sizes[3];
    const int E = in_sizes[1] / 2;
    const int B = in_sizes[2] / 8;

    const int* src = eidx;
    const int* dst = eidx + E;

    auto cdiv = [](long a, long b) { return (int)((a + b - 1) / b); };
    const int NBLK = cdiv(N, 256);      // scan blocks (must be <= 256)

    // workspace layout
    char* w = (char*)d_ws;
    float* dinv   = (float*)w;            w += (size_t)N * 4;
    int*   deg_i  = (int*)w;              w += (size_t)N * 4;   // reused as cursor
    int*   rowptr = (int*)w;              w += (size_t)(N + 1) * 4;
    int*   bsum   = (int*)w;              w += 256 * 4;
    int*   cnt_i  = (int*)w;              w += (size_t)B * 4;
    int*   brow   = (int*)w;              w += (size_t)(B + 1) * 4;
    int*   csrc   = (int*)w;              w += (size_t)E * 4;
    float* cwv    = (float*)w;            w += (size_t)E * 4;
    float* seq    = (float*)w;            w += (size_t)B * TT * 64 * 4;
    float* buf0   = (float*)w;            w += (size_t)N * 64 * 4;
    float* buf1   = (float*)w;            w += (size_t)N * 64 * 4;
    float* buf2   = (float*)w;            w += (size_t)N * 64 * 4;

    float* out_attn = (float*)d_out;
    float* out_cls  = out_attn + (long)B * TT;

    // ---- CSR build (once per call) ----
    hipMemsetAsync(deg_i, 0, (size_t)N * 4, stream);
    hipMemsetAsync(cnt_i, 0, (size_t)B * 4, stream);
    degi_kernel<<<cdiv(E, 256), 256, 0, stream>>>(dst, deg_i, E);
    cnti_kernel<<<cdiv(N, 256), 256, 0, stream>>>(batch, cnt_i, N);
    dinv_kernel<<<cdiv(N, 256), 256, 0, stream>>>(deg_i, dinv, N);
    scan_local<<<NBLK, 256, 0, stream>>>(deg_i, rowptr, bsum, N);
    scan_bsum<<<1, 256, 0, stream>>>(bsum, NBLK);
    scan_add<<<NBLK, 256, 0, stream>>>(rowptr, deg_i /*cursor*/, bsum, N, E);
    scan_brow<<<1, 256, 0, stream>>>(cnt_i, brow, B, N);
    fill_csr<<<cdiv(E, 256), 256, 0, stream>>>(src, dst, dinv, deg_i /*cursor*/,
                                               csrc, cwv, E);

    const int gemm_grid = cdiv(N, 64);
    const int nw_grid   = cdiv((long)N * 64, 256);

    for (int ch = 0; ch < TT; ++ch) {
        gemm64_kernel<<<gemm_grid, 256, 0, stream>>>(x + ch * 64, 3 * 64, lin_W, lin_b, buf0, N);
        gemm64_kernel<<<gemm_grid, 256, 0, stream>>>(buf0, 64, conv1_W, nullptr, buf1, N);
        gcn_gather<true><<<nw_grid, 256, 0, stream>>>(rowptr, csrc, cwv, dinv, buf1,
                                                      conv1_b, buf0, buf2, N);
        gemm64_kernel<<<gemm_grid, 256, 0, stream>>>(buf2, 64, conv2_W, nullptr, buf1, N);
        gcn_gather<false><<<nw_grid, 256, 0, stream>>>(rowptr, csrc, cwv, dinv, buf1,
                                                       conv2_b, buf2, buf0, N);
        pool_range<<<B, 256, 0, stream>>>(buf0, brow, seq, ch);
    }

    head_kernel<<<B, 256, 0, stream>>>(seq, cnt_i, h0, c0, Wih, Whh, bih, bhh,
                                       w0_W, w0_b, attn_W, attn_b, l1_W, l1_b,
                                       l2_W, l2_b, cov, out_attn, out_cls);
}

// Round 9
// 519.199 us; speedup vs baseline: 3.0958x; 1.5993x over previous
//
#include <hip/hip_runtime.h>
#include <math.h>

// ---------------------------------------------------------------------------
// temporalGNN fp32.  R4 (resubmit x5 after container failures):
//  - cnti atomics -> sorted-batch boundary detection (brow ranges)
//  - fill_csr: drop cw array (recompute norm from L2-resident dinv in gather)
//  - GEMM: transposed-A LDS tile + 4x4 register blocking (2 b128 per 16 FMA)
//  - batch 3 channels per stage launch via grid.y when workspace permits
// ---------------------------------------------------------------------------

#define TT 3

__device__ __forceinline__ float sigmoidf_(float x) { return 1.f / (1.f + expf(-x)); }

// ---- integer degree ------------------------------------------------------
__global__ void degi_kernel(const int* __restrict__ dst, int* __restrict__ deg, int E) {
    int e = blockIdx.x * blockDim.x + threadIdx.x;
    if (e < E) atomicAdd(&deg[dst[e]], 1);
}
__global__ void dinv_kernel(const int* __restrict__ deg, float* __restrict__ dinv, int N) {
    int n = blockIdx.x * blockDim.x + threadIdx.x;
    if (n < N) dinv[n] = rsqrtf((float)deg[n] + 2.0f);
}

// ---- batch ranges from sorted batch vector -------------------------------
__global__ void brow_sorted(const int* __restrict__ batch, int* __restrict__ brow,
                            int N, int B) {
    int n = blockIdx.x * 256 + threadIdx.x;
    if (n >= N) return;
    int b = batch[n];
    if (n == 0) {
        for (int q = 0; q <= b; ++q) brow[q] = 0;
    } else {
        int pb = batch[n - 1];
        for (int q = pb + 1; q <= b; ++q) brow[q] = n;
    }
    if (n == N - 1) {
        for (int q = b + 1; q <= B; ++q) brow[q] = N;
    }
}

// ---- exclusive scan (3-kernel) -------------------------------------------
__global__ void scan_local(const int* __restrict__ deg, int* __restrict__ rowptr,
                           int* __restrict__ bsum, int N) {
    __shared__ int s[256];
    int i = blockIdx.x * 256 + threadIdx.x;
    int v = (i < N) ? deg[i] : 0;
    s[threadIdx.x] = v;
    __syncthreads();
    for (int off = 1; off < 256; off <<= 1) {
        int t = (threadIdx.x >= off) ? s[threadIdx.x - off] : 0;
        __syncthreads();
        s[threadIdx.x] += t;
        __syncthreads();
    }
    if (i < N) rowptr[i] = s[threadIdx.x] - v;
    if (threadIdx.x == 255) bsum[blockIdx.x] = s[255];
}
__global__ void scan_bsum(int* __restrict__ bsum, int nblk) {
    __shared__ int s[256];
    int v = (threadIdx.x < nblk) ? bsum[threadIdx.x] : 0;
    s[threadIdx.x] = v;
    __syncthreads();
    for (int off = 1; off < 256; off <<= 1) {
        int t = (threadIdx.x >= off) ? s[threadIdx.x - off] : 0;
        __syncthreads();
        s[threadIdx.x] += t;
        __syncthreads();
    }
    if (threadIdx.x < nblk) bsum[threadIdx.x] = s[threadIdx.x] - v;
}
__global__ void scan_add(int* __restrict__ rowptr, int* __restrict__ cursor,
                         const int* __restrict__ bsum, int N, int E) {
    int i = blockIdx.x * 256 + threadIdx.x;
    if (i < N) {
        int r = rowptr[i] + bsum[blockIdx.x];
        rowptr[i] = r;
        cursor[i] = r;
    }
    if (i == 0) rowptr[N] = E;
}

// ---- CSR fill (src only; norm recomputed later) --------------------------
__global__ void fill_csr(const int* __restrict__ src, const int* __restrict__ dst,
                         int* __restrict__ cursor, int* __restrict__ csrc, int E) {
    int e = blockIdx.x * blockDim.x + threadIdx.x;
    if (e >= E) return;
    int p = atomicAdd(&cursor[dst[e]], 1);
    csrc[p] = src[e];
}

// ---- GEMM v2: C[., r,64] = A[., r,64(lda)] @ W[64,64] (+bias) -------------
// 64 rows x 64 cols per block; 4x4 register tile; 2 ds_read_b128 per 16 FMA.
__global__ __launch_bounds__(256) void gemm64_v2(
    const float* __restrict__ A, int lda, long aStride,
    const float* __restrict__ W, const float* __restrict__ bias,
    float* __restrict__ C, long cStride, int nrows) {
    __shared__ float AT[64][68];   // AT[k][row]
    __shared__ float Ws[64][68];   // Ws[k][col]
    const int t = threadIdx.x;
    const float* Ab = A + (long)blockIdx.y * aStride;
    float* Cb = C + (long)blockIdx.y * cStride;
    const int r0 = blockIdx.x * 64;

    #pragma unroll
    for (int i = 0; i < 4; ++i) {
        int idx = t + i * 256;
        int k = idx >> 4, c4 = idx & 15;
        float4 w = *(const float4*)(W + k * 64 + c4 * 4);
        *(float4*)&Ws[k][c4 * 4] = w;
    }
    #pragma unroll
    for (int i = 0; i < 4; ++i) {
        int idx = t + i * 256;
        int row = idx >> 4, c4 = idx & 15;
        int gr = r0 + row;
        float4 a = make_float4(0.f, 0.f, 0.f, 0.f);
        if (gr < nrows) a = *(const float4*)(Ab + (long)gr * lda + c4 * 4);
        AT[c4 * 4 + 0][row] = a.x;
        AT[c4 * 4 + 1][row] = a.y;
        AT[c4 * 4 + 2][row] = a.z;
        AT[c4 * 4 + 3][row] = a.w;
    }
    __syncthreads();

    const int rowg = t >> 4;     // 0..15
    const int colg = t & 15;     // 0..15
    float acc[4][4] = {};
    #pragma unroll 8
    for (int k = 0; k < 64; ++k) {
        float4 av = *(const float4*)&AT[k][rowg * 4];
        float4 wv = *(const float4*)&Ws[k][colg * 4];
        acc[0][0] = fmaf(av.x, wv.x, acc[0][0]);
        acc[0][1] = fmaf(av.x, wv.y, acc[0][1]);
        acc[0][2] = fmaf(av.x, wv.z, acc[0][2]);
        acc[0][3] = fmaf(av.x, wv.w, acc[0][3]);
        acc[1][0] = fmaf(av.y, wv.x, acc[1][0]);
        acc[1][1] = fmaf(av.y, wv.y, acc[1][1]);
        acc[1][2] = fmaf(av.y, wv.z, acc[1][2]);
        acc[1][3] = fmaf(av.y, wv.w, acc[1][3]);
        acc[2][0] = fmaf(av.z, wv.x, acc[2][0]);
        acc[2][1] = fmaf(av.z, wv.y, acc[2][1]);
        acc[2][2] = fmaf(av.z, wv.z, acc[2][2]);
        acc[2][3] = fmaf(av.z, wv.w, acc[2][3]);
        acc[3][0] = fmaf(av.w, wv.x, acc[3][0]);
        acc[3][1] = fmaf(av.w, wv.y, acc[3][1]);
        acc[3][2] = fmaf(av.w, wv.z, acc[3][2]);
        acc[3][3] = fmaf(av.w, wv.w, acc[3][3]);
    }

    float b0 = bias ? bias[colg * 4 + 0] : 0.f;
    float b1 = bias ? bias[colg * 4 + 1] : 0.f;
    float b2 = bias ? bias[colg * 4 + 2] : 0.f;
    float b3 = bias ? bias[colg * 4 + 3] : 0.f;
    #pragma unroll
    for (int i = 0; i < 4; ++i) {
        int gr = r0 + rowg * 4 + i;
        if (gr < nrows) {
            float4 o = make_float4(acc[i][0] + b0, acc[i][1] + b1,
                                   acc[i][2] + b2, acc[i][3] + b3);
            *(float4*)(Cb + (long)gr * 64 + colg * 4) = o;
        }
    }
}

// ---- fused GCN step: gather + self-loop + bias (+relu) + residual ---------
template <bool RELU>
__global__ __launch_bounds__(256) void gcn_gather(
    const int* __restrict__ rowptr, const int* __restrict__ csrc,
    const float* __restrict__ dinv, const float* __restrict__ xw, long chStride,
    const float* __restrict__ bias, const float* __restrict__ prev,
    float* __restrict__ outp, int N) {
    long tid = (long)blockIdx.x * 256 + threadIdx.x;
    int n = (int)(tid >> 6);
    int j = (int)(tid & 63);
    if (n >= N) return;
    const float* xwc = xw + (long)blockIdx.y * chStride;
    const float* pvc = prev + (long)blockIdx.y * chStride;
    float* outc = outp + (long)blockIdx.y * chStride;

    int p = rowptr[n];
    const int end = rowptr[n + 1];
    const float din = dinv[n];
    float acc = 0.f;
    for (; p + 1 < end; p += 2) {
        int s0 = csrc[p], s1 = csrc[p + 1];
        float w0 = dinv[s0] * din, w1 = dinv[s1] * din;
        acc = fmaf(w0, xwc[(long)s0 * 64 + j], acc);
        acc = fmaf(w1, xwc[(long)s1 * 64 + j], acc);
    }
    if (p < end) {
        int s0 = csrc[p];
        acc = fmaf(dinv[s0] * din, xwc[(long)s0 * 64 + j], acc);
    }
    long off = (long)n * 64 + j;
    float val = acc + 2.f * din * din * xwc[off] + bias[j];
    if (RELU) val = fmaxf(val, 0.f);
    outc[off] = val + pvc[off];
}

// ---- range-based pool numerator ------------------------------------------
__global__ __launch_bounds__(256) void pool_range(
    const float* __restrict__ out2, long chStride, const int* __restrict__ brow,
    float* __restrict__ seq, int chan_base) {
    const int b = blockIdx.x;
    const int chan = chan_base + blockIdx.y;
    const float* src = out2 + (long)blockIdx.y * chStride;
    const int j = threadIdx.x & 63;
    const int w = threadIdx.x >> 6;
    __shared__ float part[4][64];
    float acc = 0.f;
    const int s = brow[b], e = brow[b + 1];
    for (int n = s + w; n < e; n += 4) acc += src[(long)n * 64 + j];
    part[w][j] = acc;
    __syncthreads();
    if (w == 0)
        seq[((long)b * TT + chan) * 64 + j] = part[0][j] + part[1][j] + part[2][j] + part[3][j];
}

// ---- head ----------------------------------------------------------------
__global__ __launch_bounds__(256) void head_kernel(
    const float* __restrict__ seq, const int* __restrict__ brow,
    const float* __restrict__ h0, const float* __restrict__ c0,
    const float* __restrict__ Wih, const float* __restrict__ Whh,
    const float* __restrict__ bih, const float* __restrict__ bhh,
    const float* __restrict__ w0W, const float* __restrict__ w0b,
    const float* __restrict__ attnW, const float* __restrict__ attnb,
    const float* __restrict__ l1W, const float* __restrict__ l1b,
    const float* __restrict__ l2W, const float* __restrict__ l2b,
    const float* __restrict__ cov, float* __restrict__ out_attn,
    float* __restrict__ out_cls) {
    const int b = blockIdx.x;
    const int t = threadIdx.x;

    __shared__ float x[TT][64];
    __shared__ float h[64], c[64];
    __shared__ float gates[256];
    __shared__ float rnn[TT][64];
    __shared__ float r[TT][64];
    __shared__ float logit[TT];
    __shared__ float a[TT];
    __shared__ float pooled[64];
    __shared__ float l1o[16];

    float inv = 1.0f / fmaxf((float)(brow[b + 1] - brow[b]), 1.0f);
    if (t < TT * 64) x[t / 64][t % 64] = seq[(long)b * TT * 64 + t] * inv;
    if (t < 64) { h[t] = h0[(long)b * 64 + t]; c[t] = c0[(long)b * 64 + t]; }
    __syncthreads();

    for (int step = 0; step < TT; ++step) {
        float g = bih[t] + bhh[t];
        const float* wi = Wih + (long)t * 64;
        const float* wh = Whh + (long)t * 64;
        #pragma unroll 8
        for (int k = 0; k < 64; ++k) g += wi[k] * x[step][k] + wh[k] * h[k];
        gates[t] = g;
        __syncthreads();
        if (t < 64) {
            float ig = sigmoidf_(gates[t]);
            float fg = sigmoidf_(gates[64 + t]);
            float gg = tanhf(gates[128 + t]);
            float og = sigmoidf_(gates[192 + t]);
            float cn = fg * c[t] + ig * gg;
            c[t] = cn;
            float hn = og * tanhf(cn);
            h[t] = hn;
            rnn[step][t] = hn;
        }
        __syncthreads();
    }

    if (t < TT * 64) {
        int tt = t / 64, j = t % 64;
        float v = w0b[j];
        const float* wr = w0W + (long)j * 64;
        #pragma unroll 8
        for (int k = 0; k < 64; ++k) v += rnn[tt][k] * wr[k];
        r[tt][j] = tanhf(v);
    }
    __syncthreads();

    if (t < TT) {
        float v = attnb[0];
        #pragma unroll 8
        for (int k = 0; k < 64; ++k) v += r[t][k] * attnW[k];
        logit[t] = v;
    }
    __syncthreads();

    if (t == 0) {
        float m = fmaxf(logit[0], fmaxf(logit[1], logit[2]));
        float e0 = expf(logit[0] - m), e1 = expf(logit[1] - m), e2 = expf(logit[2] - m);
        float s = e0 + e1 + e2;
        a[0] = e0 / s; a[1] = e1 / s; a[2] = e2 / s;
        out_attn[(long)b * TT + 0] = a[0];
        out_attn[(long)b * TT + 1] = a[1];
        out_attn[(long)b * TT + 2] = a[2];
    }
    __syncthreads();

    if (t < 64) pooled[t] = a[0] * r[0][t] + a[1] * r[1][t] + a[2] * r[2][t];
    __syncthreads();

    if (t < 8) {
        float v = l1b[t];
        const float* w = l1W + (long)t * 64;
        #pragma unroll 8
        for (int k = 0; k < 64; ++k) v += pooled[k] * w[k];
        l1o[t] = fmaxf(v, 0.f);
    } else if (t < 16) {
        l1o[t] = cov[(long)b * 8 + (t - 8)];
    }
    __syncthreads();

    if (t < 2) {
        float v = l2b[t];
        const float* w = l2W + (long)t * 16;
        #pragma unroll
        for (int k = 0; k < 16; ++k) v += l1o[k] * w[k];
        out_cls[(long)b * 2 + t] = v;
    }
}

// ---------------------------------------------------------------------------
extern "C" void kernel_launch(void* const* d_in, const int* in_sizes, int n_in,
                              void* d_out, int out_size, void* d_ws, size_t ws_size,
                              hipStream_t stream) {
    const float* x       = (const float*)d_in[0];
    const int*   eidx    = (const int*)d_in[1];
    const float* cov     = (const float*)d_in[2];
    const int*   batch   = (const int*)d_in[3];
    const float* h0      = (const float*)d_in[4];
    const float* c0      = (const float*)d_in[5];
    const float* lin_W   = (const float*)d_in[6];
    const float* lin_b   = (const float*)d_in[7];
    const float* conv1_W = (const float*)d_in[8];
    const float* conv1_b = (const float*)d_in[9];
    const float* conv2_W = (const float*)d_in[10];
    const float* conv2_b = (const float*)d_in[11];
    const float* Wih     = (const float*)d_in[12];
    const float* Whh     = (const float*)d_in[13];
    const float* bih     = (const float*)d_in[14];
    const float* bhh     = (const float*)d_in[15];
    const float* w0_W    = (const float*)d_in[16];
    const float* w0_b    = (const float*)d_in[17];
    const float* attn_W  = (const float*)d_in[18];
    const float* attn_b  = (const float*)d_in[19];
    const float* l1_W    = (const float*)d_in[20];
    const float* l1_b    = (const float*)d_in[21];
    const float* l2_W    = (const float*)d_in[22];
    const float* l2_b    = (const float*)d_in[23];

    const int N = in_sizes[3];
    const int E = in_sizes[1] / 2;
    const int B = in_sizes[2] / 8;

    const int* src = eidx;
    const int* dst = eidx + E;

    auto cdiv = [](long a, long b) { return (int)((a + b - 1) / b); };
    const int NBLK = cdiv(N, 256);

    // fixed-part workspace
    char* w = (char*)d_ws;
    float* dinv   = (float*)w;  w += (size_t)N * 4;
    int*   deg_i  = (int*)w;    w += (size_t)N * 4;        // reused as cursor
    int*   rowptr = (int*)w;    w += (size_t)(N + 1) * 4;
    int*   bsum   = (int*)w;    w += 256 * 4;
    int*   brow   = (int*)w;    w += (size_t)(B + 1) * 4;
    int*   csrc   = (int*)w;    w += (size_t)E * 4;
    float* seq    = (float*)w;  w += (size_t)B * TT * 64 * 4;
    size_t fixed  = (size_t)(w - (char*)d_ws);

    // channel-batched buffers if workspace allows (3 bufs x nch x N*64 floats)
    size_t bufBytes1 = (size_t)N * 64 * 4;
    int nch = (ws_size - fixed >= 3 * 3 * bufBytes1) ? 3 : 1;
    float* buf0 = (float*)w;  w += 3 * (size_t)nch * bufBytes1;  // buf0|buf1|buf2
    float* buf1 = buf0 + (size_t)nch * N * 64;
    float* buf2 = buf1 + (size_t)nch * N * 64;
    const long chS = (long)N * 64;   // channel stride within a buffer

    float* out_attn = (float*)d_out;
    float* out_cls  = out_attn + (long)B * TT;

    // ---- CSR build ----
    hipMemsetAsync(deg_i, 0, (size_t)N * 4, stream);
    degi_kernel<<<cdiv(E, 256), 256, 0, stream>>>(dst, deg_i, E);
    brow_sorted<<<cdiv(N, 256), 256, 0, stream>>>(batch, brow, N, B);
    dinv_kernel<<<cdiv(N, 256), 256, 0, stream>>>(deg_i, dinv, N);
    scan_local<<<NBLK, 256, 0, stream>>>(deg_i, rowptr, bsum, N);
    scan_bsum<<<1, 256, 0, stream>>>(bsum, NBLK);
    scan_add<<<NBLK, 256, 0, stream>>>(rowptr, deg_i /*cursor*/, bsum, N, E);
    fill_csr<<<cdiv(E, 256), 256, 0, stream>>>(src, dst, deg_i /*cursor*/, csrc, E);

    const int gemm_gx = cdiv(N, 64);
    const int nw_gx   = cdiv((long)N * 64, 256);

    const int outer = (nch == 3) ? 1 : 3;
    for (int oc = 0; oc < outer; ++oc) {
        dim3 ggrid(gemm_gx, nch), ngrid(nw_gx, nch), pgrid(B, nch);
        // lin: A = x[:, ch*64 : ch*64+64], lda=192, chan stride 64
        gemm64_v2<<<ggrid, 256, 0, stream>>>(x + (nch == 3 ? 0 : oc) * 64, 3 * 64,
                                             64, lin_W, lin_b, buf0, chS, N);
        // conv1 xw
        gemm64_v2<<<ggrid, 256, 0, stream>>>(buf0, 64, chS, conv1_W, nullptr, buf1, chS, N);
        gcn_gather<true><<<ngrid, 256, 0, stream>>>(rowptr, csrc, dinv, buf1, chS,
                                                    conv1_b, buf0, buf2, N);
        // conv2 xw
        gemm64_v2<<<ggrid, 256, 0, stream>>>(buf2, 64, chS, conv2_W, nullptr, buf1, chS, N);
        gcn_gather<false><<<ngrid, 256, 0, stream>>>(rowptr, csrc, dinv, buf1, chS,
                                                     conv2_b, buf2, buf0, N);
        pool_range<<<pgrid, 256, 0, stream>>>(buf0, chS, brow, seq, (nch == 3 ? 0 : oc));
    }

    head_kernel<<<B, 256, 0, stream>>>(seq, brow, h0, c0, Wih, Whh, bih, bhh,
                                       w0_W, w0_b, attn_W, attn_b, l1_W, l1_b,
                                       l2_W, l2_b, cov, out_attn, out_cls);
}

// Round 12
// 404.701 us; speedup vs baseline: 3.9716x; 1.2829x over previous
//
#include <hip/hip_runtime.h>
#include <math.h>

// ---------------------------------------------------------------------------
// temporalGNN fp32.  R5 (resubmit x2 after container failures):
//  - conv xw -> bf16 gather table pre-scaled by dinv[src]; fp32 xw bufs gone
//  - gather: 2 edges/wave (32-lane halves, bf16x2 loads) + 4-edge unroll
//    => 8 edges in flight/wave; self-loop read from table; no dinv[src] loads
// ---------------------------------------------------------------------------

#define TT 3

__device__ __forceinline__ float sigmoidf_(float x) { return 1.f / (1.f + expf(-x)); }
__device__ __forceinline__ float bflo(unsigned u) { return __uint_as_float(u << 16); }
__device__ __forceinline__ float bfhi(unsigned u) { return __uint_as_float(u & 0xFFFF0000u); }
__device__ __forceinline__ unsigned short f2bf(float f) {
    unsigned u = __float_as_uint(f);
    u += 0x7FFFu + ((u >> 16) & 1u);          // round-to-nearest-even
    return (unsigned short)(u >> 16);
}

// ---- integer degree ------------------------------------------------------
__global__ void degi_kernel(const int* __restrict__ dst, int* __restrict__ deg, int E) {
    int e = blockIdx.x * blockDim.x + threadIdx.x;
    if (e < E) atomicAdd(&deg[dst[e]], 1);
}
__global__ void dinv_kernel(const int* __restrict__ deg, float* __restrict__ dinv, int N) {
    int n = blockIdx.x * blockDim.x + threadIdx.x;
    if (n < N) dinv[n] = rsqrtf((float)deg[n] + 2.0f);
}

// ---- batch ranges from sorted batch vector -------------------------------
__global__ void brow_sorted(const int* __restrict__ batch, int* __restrict__ brow,
                            int N, int B) {
    int n = blockIdx.x * 256 + threadIdx.x;
    if (n >= N) return;
    int b = batch[n];
    if (n == 0) {
        for (int q = 0; q <= b; ++q) brow[q] = 0;
    } else {
        int pb = batch[n - 1];
        for (int q = pb + 1; q <= b; ++q) brow[q] = n;
    }
    if (n == N - 1) {
        for (int q = b + 1; q <= B; ++q) brow[q] = N;
    }
}

// ---- exclusive scan (3-kernel) -------------------------------------------
__global__ void scan_local(const int* __restrict__ deg, int* __restrict__ rowptr,
                           int* __restrict__ bsum, int N) {
    __shared__ int s[256];
    int i = blockIdx.x * 256 + threadIdx.x;
    int v = (i < N) ? deg[i] : 0;
    s[threadIdx.x] = v;
    __syncthreads();
    for (int off = 1; off < 256; off <<= 1) {
        int t = (threadIdx.x >= off) ? s[threadIdx.x - off] : 0;
        __syncthreads();
        s[threadIdx.x] += t;
        __syncthreads();
    }
    if (i < N) rowptr[i] = s[threadIdx.x] - v;
    if (threadIdx.x == 255) bsum[blockIdx.x] = s[255];
}
__global__ void scan_bsum(int* __restrict__ bsum, int nblk) {
    __shared__ int s[256];
    int v = (threadIdx.x < nblk) ? bsum[threadIdx.x] : 0;
    s[threadIdx.x] = v;
    __syncthreads();
    for (int off = 1; off < 256; off <<= 1) {
        int t = (threadIdx.x >= off) ? s[threadIdx.x - off] : 0;
        __syncthreads();
        s[threadIdx.x] += t;
        __syncthreads();
    }
    if (threadIdx.x < nblk) bsum[threadIdx.x] = s[threadIdx.x] - v;
}
__global__ void scan_add(int* __restrict__ rowptr, int* __restrict__ cursor,
                         const int* __restrict__ bsum, int N, int E) {
    int i = blockIdx.x * 256 + threadIdx.x;
    if (i < N) {
        int r = rowptr[i] + bsum[blockIdx.x];
        rowptr[i] = r;
        cursor[i] = r;
    }
    if (i == 0) rowptr[N] = E;
}

// ---- CSR fill ------------------------------------------------------------
__global__ void fill_csr(const int* __restrict__ src, const int* __restrict__ dst,
                         int* __restrict__ cursor, int* __restrict__ csrc, int E) {
    int e = blockIdx.x * blockDim.x + threadIdx.x;
    if (e >= E) return;
    int p = atomicAdd(&cursor[dst[e]], 1);
    csrc[p] = src[e];
}

// ---- GEMM: C fp32 (optional) and/or bf16 table scaled by dinv (optional) --
__global__ __launch_bounds__(256) void gemm64_v2(
    const float* __restrict__ A, int lda, long aStride,
    const float* __restrict__ W, const float* __restrict__ bias,
    float* __restrict__ C, long cStride,
    unsigned short* __restrict__ B16, long bStrideH,
    const float* __restrict__ dinvp, int nrows) {
    __shared__ float AT[64][68];   // AT[k][row]
    __shared__ float Ws[64][68];   // Ws[k][col]
    const int t = threadIdx.x;
    const float* Ab = A + (long)blockIdx.y * aStride;
    const int r0 = blockIdx.x * 64;

    #pragma unroll
    for (int i = 0; i < 4; ++i) {
        int idx = t + i * 256;
        int k = idx >> 4, c4 = idx & 15;
        float4 w = *(const float4*)(W + k * 64 + c4 * 4);
        *(float4*)&Ws[k][c4 * 4] = w;
    }
    #pragma unroll
    for (int i = 0; i < 4; ++i) {
        int idx = t + i * 256;
        int row = idx >> 4, c4 = idx & 15;
        int gr = r0 + row;
        float4 a = make_float4(0.f, 0.f, 0.f, 0.f);
        if (gr < nrows) a = *(const float4*)(Ab + (long)gr * lda + c4 * 4);
        AT[c4 * 4 + 0][row] = a.x;
        AT[c4 * 4 + 1][row] = a.y;
        AT[c4 * 4 + 2][row] = a.z;
        AT[c4 * 4 + 3][row] = a.w;
    }
    __syncthreads();

    const int rowg = t >> 4;     // 0..15
    const int colg = t & 15;     // 0..15
    float acc[4][4] = {};
    #pragma unroll 8
    for (int k = 0; k < 64; ++k) {
        float4 av = *(const float4*)&AT[k][rowg * 4];
        float4 wv = *(const float4*)&Ws[k][colg * 4];
        acc[0][0] = fmaf(av.x, wv.x, acc[0][0]);
        acc[0][1] = fmaf(av.x, wv.y, acc[0][1]);
        acc[0][2] = fmaf(av.x, wv.z, acc[0][2]);
        acc[0][3] = fmaf(av.x, wv.w, acc[0][3]);
        acc[1][0] = fmaf(av.y, wv.x, acc[1][0]);
        acc[1][1] = fmaf(av.y, wv.y, acc[1][1]);
        acc[1][2] = fmaf(av.y, wv.z, acc[1][2]);
        acc[1][3] = fmaf(av.y, wv.w, acc[1][3]);
        acc[2][0] = fmaf(av.z, wv.x, acc[2][0]);
        acc[2][1] = fmaf(av.z, wv.y, acc[2][1]);
        acc[2][2] = fmaf(av.z, wv.z, acc[2][2]);
        acc[2][3] = fmaf(av.z, wv.w, acc[2][3]);
        acc[3][0] = fmaf(av.w, wv.x, acc[3][0]);
        acc[3][1] = fmaf(av.w, wv.y, acc[3][1]);
        acc[3][2] = fmaf(av.w, wv.z, acc[3][2]);
        acc[3][3] = fmaf(av.w, wv.w, acc[3][3]);
    }

    float b0 = bias ? bias[colg * 4 + 0] : 0.f;
    float b1 = bias ? bias[colg * 4 + 1] : 0.f;
    float b2 = bias ? bias[colg * 4 + 2] : 0.f;
    float b3 = bias ? bias[colg * 4 + 3] : 0.f;
    #pragma unroll
    for (int i = 0; i < 4; ++i) {
        int gr = r0 + rowg * 4 + i;
        if (gr >= nrows) continue;
        float c0 = acc[i][0] + b0, c1 = acc[i][1] + b1;
        float c2 = acc[i][2] + b2, c3 = acc[i][3] + b3;
        if (C) {
            float* Cb = C + (long)blockIdx.y * cStride;
            *(float4*)(Cb + (long)gr * 64 + colg * 4) = make_float4(c0, c1, c2, c3);
        }
        if (B16) {
            unsigned short* Tb = B16 + (long)blockIdx.y * bStrideH;
            float sc = dinvp[gr];
            ushort4 hq;
            hq.x = f2bf(c0 * sc); hq.y = f2bf(c1 * sc);
            hq.z = f2bf(c2 * sc); hq.w = f2bf(c3 * sc);
            *(ushort4*)(Tb + (long)gr * 64 + colg * 4) = hq;
        }
    }
}

// ---- fused GCN step from bf16 table ---------------------------------------
// wave = 1 node; two 32-lane halves each process alternate edges; lane jj
// owns feature pair (2jj, 2jj+1) via bf16x2 loads.  4-edge unroll per half.
template <bool RELU>
__global__ __launch_bounds__(256) void gcn_gather_b16(
    const int* __restrict__ rowptr, const int* __restrict__ csrc,
    const float* __restrict__ dinv, const unsigned* __restrict__ tb, long chStrideU,
    const float* __restrict__ bias, const float* __restrict__ prev, long chStride,
    float* __restrict__ outp, int N) {
    long tid = (long)blockIdx.x * 256 + threadIdx.x;
    int n = (int)(tid >> 6);
    if (n >= N) return;
    const int lane = threadIdx.x & 63;
    const int jj = lane & 31;      // feature pair index
    const int half = lane >> 5;
    const unsigned* tc = tb + (long)blockIdx.y * chStrideU;     // [N][32] uints
    const float* pvc = prev + (long)blockIdx.y * chStride;
    float* outc = outp + (long)blockIdx.y * chStride;

    const int end = rowptr[n + 1];
    const float din = dinv[n];
    float a0 = 0.f, a1 = 0.f;
    int p = rowptr[n] + half;
    for (; p + 6 < end; p += 8) {              // 4 edges per half per iter
        int s0 = csrc[p], s1 = csrc[p + 2], s2 = csrc[p + 4], s3 = csrc[p + 6];
        unsigned u0 = tc[(long)s0 * 32 + jj];
        unsigned u1 = tc[(long)s1 * 32 + jj];
        unsigned u2 = tc[(long)s2 * 32 + jj];
        unsigned u3 = tc[(long)s3 * 32 + jj];
        a0 += (bflo(u0) + bflo(u1)) + (bflo(u2) + bflo(u3));
        a1 += (bfhi(u0) + bfhi(u1)) + (bfhi(u2) + bfhi(u3));
    }
    for (; p < end; p += 2) {
        unsigned u = tc[(long)csrc[p] * 32 + jj];
        a0 += bflo(u);
        a1 += bfhi(u);
    }
    a0 += __shfl_xor(a0, 32);
    a1 += __shfl_xor(a1, 32);
    if (half == 0) {
        unsigned us = tc[(long)n * 32 + jj];              // self row (pre-scaled)
        float2 bv = *(const float2*)(bias + 2 * jj);
        float v0 = (a0 + 2.f * bflo(us)) * din + bv.x;
        float v1 = (a1 + 2.f * bfhi(us)) * din + bv.y;
        if (RELU) { v0 = fmaxf(v0, 0.f); v1 = fmaxf(v1, 0.f); }
        long off = (long)n * 64 + 2 * jj;
        float2 pv = *(const float2*)(pvc + off);
        *(float2*)(outc + off) = make_float2(v0 + pv.x, v1 + pv.y);
    }
}

// ---- range-based pool numerator ------------------------------------------
__global__ __launch_bounds__(256) void pool_range(
    const float* __restrict__ out2, long chStride, const int* __restrict__ brow,
    float* __restrict__ seq, int chan_base) {
    const int b = blockIdx.x;
    const int chan = chan_base + blockIdx.y;
    const float* src = out2 + (long)blockIdx.y * chStride;
    const int j = threadIdx.x & 63;
    const int w = threadIdx.x >> 6;
    __shared__ float part[4][64];
    float acc = 0.f;
    const int s = brow[b], e = brow[b + 1];
    for (int n = s + w; n < e; n += 4) acc += src[(long)n * 64 + j];
    part[w][j] = acc;
    __syncthreads();
    if (w == 0)
        seq[((long)b * TT + chan) * 64 + j] = part[0][j] + part[1][j] + part[2][j] + part[3][j];
}

// ---- head ----------------------------------------------------------------
__global__ __launch_bounds__(256) void head_kernel(
    const float* __restrict__ seq, const int* __restrict__ brow,
    const float* __restrict__ h0, const float* __restrict__ c0,
    const float* __restrict__ Wih, const float* __restrict__ Whh,
    const float* __restrict__ bih, const float* __restrict__ bhh,
    const float* __restrict__ w0W, const float* __restrict__ w0b,
    const float* __restrict__ attnW, const float* __restrict__ attnb,
    const float* __restrict__ l1W, const float* __restrict__ l1b,
    const float* __restrict__ l2W, const float* __restrict__ l2b,
    const float* __restrict__ cov, float* __restrict__ out_attn,
    float* __restrict__ out_cls) {
    const int b = blockIdx.x;
    const int t = threadIdx.x;

    __shared__ float x[TT][64];
    __shared__ float h[64], c[64];
    __shared__ float gates[256];
    __shared__ float rnn[TT][64];
    __shared__ float r[TT][64];
    __shared__ float logit[TT];
    __shared__ float a[TT];
    __shared__ float pooled[64];
    __shared__ float l1o[16];

    float inv = 1.0f / fmaxf((float)(brow[b + 1] - brow[b]), 1.0f);
    if (t < TT * 64) x[t / 64][t % 64] = seq[(long)b * TT * 64 + t] * inv;
    if (t < 64) { h[t] = h0[(long)b * 64 + t]; c[t] = c0[(long)b * 64 + t]; }
    __syncthreads();

    for (int step = 0; step < TT; ++step) {
        float g = bih[t] + bhh[t];
        const float* wi = Wih + (long)t * 64;
        const float* wh = Whh + (long)t * 64;
        #pragma unroll 8
        for (int k = 0; k < 64; ++k) g += wi[k] * x[step][k] + wh[k] * h[k];
        gates[t] = g;
        __syncthreads();
        if (t < 64) {
            float ig = sigmoidf_(gates[t]);
            float fg = sigmoidf_(gates[64 + t]);
            float gg = tanhf(gates[128 + t]);
            float og = sigmoidf_(gates[192 + t]);
            float cn = fg * c[t] + ig * gg;
            c[t] = cn;
            float hn = og * tanhf(cn);
            h[t] = hn;
            rnn[step][t] = hn;
        }
        __syncthreads();
    }

    if (t < TT * 64) {
        int tt = t / 64, j = t % 64;
        float v = w0b[j];
        const float* wr = w0W + (long)j * 64;
        #pragma unroll 8
        for (int k = 0; k < 64; ++k) v += rnn[tt][k] * wr[k];
        r[tt][j] = tanhf(v);
    }
    __syncthreads();

    if (t < TT) {
        float v = attnb[0];
        #pragma unroll 8
        for (int k = 0; k < 64; ++k) v += r[t][k] * attnW[k];
        logit[t] = v;
    }
    __syncthreads();

    if (t == 0) {
        float m = fmaxf(logit[0], fmaxf(logit[1], logit[2]));
        float e0 = expf(logit[0] - m), e1 = expf(logit[1] - m), e2 = expf(logit[2] - m);
        float s = e0 + e1 + e2;
        a[0] = e0 / s; a[1] = e1 / s; a[2] = e2 / s;
        out_attn[(long)b * TT + 0] = a[0];
        out_attn[(long)b * TT + 1] = a[1];
        out_attn[(long)b * TT + 2] = a[2];
    }
    __syncthreads();

    if (t < 64) pooled[t] = a[0] * r[0][t] + a[1] * r[1][t] + a[2] * r[2][t];
    __syncthreads();

    if (t < 8) {
        float v = l1b[t];
        const float* w = l1W + (long)t * 64;
        #pragma unroll 8
        for (int k = 0; k < 64; ++k) v += pooled[k] * w[k];
        l1o[t] = fmaxf(v, 0.f);
    } else if (t < 16) {
        l1o[t] = cov[(long)b * 8 + (t - 8)];
    }
    __syncthreads();

    if (t < 2) {
        float v = l2b[t];
        const float* w = l2W + (long)t * 16;
        #pragma unroll
        for (int k = 0; k < 16; ++k) v += l1o[k] * w[k];
        out_cls[(long)b * 2 + t] = v;
    }
}

// ---------------------------------------------------------------------------
extern "C" void kernel_launch(void* const* d_in, const int* in_sizes, int n_in,
                              void* d_out, int out_size, void* d_ws, size_t ws_size,
                              hipStream_t stream) {
    const float* x       = (const float*)d_in[0];
    const int*   eidx    = (const int*)d_in[1];
    const float* cov     = (const float*)d_in[2];
    const int*   batch   = (const int*)d_in[3];
    const float* h0      = (const float*)d_in[4];
    const float* c0      = (const float*)d_in[5];
    const float* lin_W   = (const float*)d_in[6];
    const float* lin_b   = (const float*)d_in[7];
    const float* conv1_W = (const float*)d_in[8];
    const float* conv1_b = (const float*)d_in[9];
    const float* conv2_W = (const float*)d_in[10];
    const float* conv2_b = (const float*)d_in[11];
    const float* Wih     = (const float*)d_in[12];
    const float* Whh     = (const float*)d_in[13];
    const float* bih     = (const float*)d_in[14];
    const float* bhh     = (const float*)d_in[15];
    const float* w0_W    = (const float*)d_in[16];
    const float* w0_b    = (const float*)d_in[17];
    const float* attn_W  = (const float*)d_in[18];
    const float* attn_b  = (const float*)d_in[19];
    const float* l1_W    = (const float*)d_in[20];
    const float* l1_b    = (const float*)d_in[21];
    const float* l2_W    = (const float*)d_in[22];
    const float* l2_b    = (const float*)d_in[23];

    const int N = in_sizes[3];
    const int E = in_sizes[1] / 2;
    const int B = in_sizes[2] / 8;

    const int* src = eidx;
    const int* dst = eidx + E;

    auto cdiv = [](long a, long b) { return (int)((a + b - 1) / b); };
    const int NBLK = cdiv(N, 256);

    // fixed-part workspace
    char* w = (char*)d_ws;
    float* dinv   = (float*)w;  w += (size_t)N * 4;
    int*   deg_i  = (int*)w;    w += (size_t)N * 4;        // reused as cursor
    int*   rowptr = (int*)w;    w += (size_t)(N + 1) * 4;
    int*   bsum   = (int*)w;    w += 256 * 4;
    int*   brow   = (int*)w;    w += (size_t)(B + 1) * 4;
    int*   csrc   = (int*)w;    w += (size_t)E * 4;
    float* seq    = (float*)w;  w += (size_t)B * TT * 64 * 4;
    size_t fixed  = (size_t)(w - (char*)d_ws);

    // per-channel buffers: 2 fp32 bufs + 1 bf16 table, batched if ws allows
    size_t f32Bytes = (size_t)N * 64 * 4;
    size_t b16Bytes = (size_t)N * 64 * 2;
    int nch = (ws_size - fixed >= 3 * (2 * f32Bytes + b16Bytes)) ? 3 : 1;
    float* buf0 = (float*)w;              w += (size_t)nch * f32Bytes;
    float* buf2 = (float*)w;              w += (size_t)nch * f32Bytes;
    unsigned short* tb16 = (unsigned short*)w;  w += (size_t)nch * b16Bytes;
    const long chS  = (long)N * 64;   // fp32 / ushort element stride per channel
    const long chSU = (long)N * 32;   // uint stride per channel (bf16x2)

    float* out_attn = (float*)d_out;
    float* out_cls  = out_attn + (long)B * TT;

    // ---- CSR build ----
    hipMemsetAsync(deg_i, 0, (size_t)N * 4, stream);
    degi_kernel<<<cdiv(E, 256), 256, 0, stream>>>(dst, deg_i, E);
    brow_sorted<<<cdiv(N, 256), 256, 0, stream>>>(batch, brow, N, B);
    dinv_kernel<<<cdiv(N, 256), 256, 0, stream>>>(deg_i, dinv, N);
    scan_local<<<NBLK, 256, 0, stream>>>(deg_i, rowptr, bsum, N);
    scan_bsum<<<1, 256, 0, stream>>>(bsum, NBLK);
    scan_add<<<NBLK, 256, 0, stream>>>(rowptr, deg_i /*cursor*/, bsum, N, E);
    fill_csr<<<cdiv(E, 256), 256, 0, stream>>>(src, dst, deg_i /*cursor*/, csrc, E);

    const int gemm_gx = cdiv(N, 64);
    const int nw_gx   = cdiv((long)N * 64, 256);

    const int outer = (nch == 3) ? 1 : 3;
    for (int oc = 0; oc < outer; ++oc) {
        dim3 ggrid(gemm_gx, nch), ngrid(nw_gx, nch), pgrid(B, nch);
        // lin: fp32 out -> buf0
        gemm64_v2<<<ggrid, 256, 0, stream>>>(x + (nch == 3 ? 0 : oc) * 64, 3 * 64,
                                             64, lin_W, lin_b, buf0, chS,
                                             nullptr, 0, nullptr, N);
        // conv1 xw -> bf16 table (pre-scaled by dinv)
        gemm64_v2<<<ggrid, 256, 0, stream>>>(buf0, 64, chS, conv1_W, nullptr,
                                             nullptr, 0, tb16, chS, dinv, N);
        gcn_gather_b16<true><<<ngrid, 256, 0, stream>>>(
            rowptr, csrc, dinv, (const unsigned*)tb16, chSU,
            conv1_b, buf0, chS, buf2, N);
        // conv2 xw -> bf16 table
        gemm64_v2<<<ggrid, 256, 0, stream>>>(buf2, 64, chS, conv2_W, nullptr,
                                             nullptr, 0, tb16, chS, dinv, N);
        gcn_gather_b16<false><<<ngrid, 256, 0, stream>>>(
            rowptr, csrc, dinv, (const unsigned*)tb16, chSU,
            conv2_b, buf2, chS, buf0, N);
        pool_range<<<pgrid, 256, 0, stream>>>(buf0, chS, brow, seq, (nch == 3 ? 0 : oc));
    }

    head_kernel<<<B, 256, 0, stream>>>(seq, brow, h0, c0, Wih, Whh, bih, bhh,
                                       w0_W, w0_b, attn_W, attn_b, l1_W, l1_b,
                                       l2_W, l2_b, cov, out_attn, out_cls);
}